// Round 16
// baseline (197.047 us; speedup 1.0000x reference)
//
#include <hip/hip_runtime.h>

#define NB  8
#define TOQ 2048
#define TIV 2048
#define HD  128

typedef float f32x4 __attribute__((ext_vector_type(4)));
typedef short s16x8 __attribute__((ext_vector_type(8)));
typedef unsigned short ushort4v __attribute__((ext_vector_type(4)));
typedef unsigned short ushort8v __attribute__((ext_vector_type(8)));

__device__ __forceinline__ unsigned short f2bf(float f) {   // RNE f32->bf16
    unsigned u = __float_as_uint(f);
    return (unsigned short)((u + 0x7FFFu + ((u >> 16) & 1u)) >> 16);
}
__device__ __forceinline__ float bf2f(unsigned short h) {
    return __uint_as_float(((unsigned)h) << 16);
}

__device__ __forceinline__ void split8(const float4 a, const float4 b,
                                       ushort8v& h, ushort8v& l) {
    const float x[8] = {a.x, a.y, a.z, a.w, b.x, b.y, b.z, b.w};
    #pragma unroll
    for (int j = 0; j < 8; ++j) {
        const unsigned short hi = f2bf(x[j]);
        h[j] = hi;
        l[j] = f2bf(x[j] - bf2f(hi));
    }
}

// async 16B global -> LDS (wave-uniform LDS base + lane*16)
__device__ __forceinline__ void gload16(const void* g, void* l) {
    __builtin_amdgcn_global_load_lds(
        (const __attribute__((address_space(1))) void*)g,
        (__attribute__((address_space(3))) void*)l, 16, 0, 0);
}

// ---------------------------------------------------------------------------
// K0a: elementwise split of Q and V into bf16 hi/lo arrays ([n][row][h]).
// ---------------------------------------------------------------------------
__global__ __launch_bounds__(256) void k0_split(
    const float* __restrict__ Q, const float* __restrict__ V,
    unsigned short* __restrict__ Qh, unsigned short* __restrict__ Ql,
    unsigned short* __restrict__ Vh, unsigned short* __restrict__ Vl)
{
    const size_t i = ((size_t)blockIdx.x * 256 + threadIdx.x) * 8;
    const float* src = blockIdx.y ? V : Q;
    unsigned short* dh = blockIdx.y ? Vh : Qh;
    unsigned short* dl = blockIdx.y ? Vl : Ql;
    const float4 a = *(const float4*)&src[i];
    const float4 b = *(const float4*)&src[i + 4];
    ushort8v h, l;
    split8(a, b, h, l);
    *(ushort8v*)&dh[i] = h;
    *(ushort8v*)&dl[i] = l;
}

// ---------------------------------------------------------------------------
// K0b: VT[n][h][s] = bf16(V[n][s][h])  (4 MB; B-fragment source for k3)
// ---------------------------------------------------------------------------
__global__ __launch_bounds__(256) void k0_vt(
    const float* __restrict__ V, unsigned short* __restrict__ VT)
{
    __shared__ unsigned short tile[64][68];
    const int n  = blockIdx.z;
    const int s0 = blockIdx.x * 64;
    const int h0 = blockIdx.y * 64;
    const int t  = threadIdx.x;

    #pragma unroll
    for (int it = 0; it < 4; ++it) {
        const int f = t + it * 256;
        const int r = f >> 4;
        const int c = f & 15;
        const float4 v = *(const float4*)&V[((size_t)(n * TIV + s0 + r)) * HD + h0 + 4 * c];
        tile[4 * c + 0][r] = f2bf(v.x);
        tile[4 * c + 1][r] = f2bf(v.y);
        tile[4 * c + 2][r] = f2bf(v.z);
        tile[4 * c + 3][r] = f2bf(v.w);
    }
    __syncthreads();

    #pragma unroll
    for (int it = 0; it < 2; ++it) {
        const int f  = t + it * 256;
        const int hh = f >> 3;
        const int sc = f & 7;
        ushort8v o;
        #pragma unroll
        for (int j = 0; j < 8; ++j) o[j] = tile[hh][8 * sc + j];
        *(ushort8v*)&VT[((size_t)(n * HD + h0 + hh)) * TIV + s0 + 8 * sc] = o;
    }
}

// ---------------------------------------------------------------------------
// K1 (tier2, r14/r15-verified): 8-wave transposed QK^T (A=V,B=Q), acc[4][2],
// global_load_lds staging of pre-split arrays, bf16 E out, fused partials.
// ---------------------------------------------------------------------------
__global__ __launch_bounds__(512) void k1_w8(
    const unsigned short* __restrict__ QhG, const unsigned short* __restrict__ QlG,
    const unsigned short* __restrict__ VhG, const unsigned short* __restrict__ VlG,
    const int* __restrict__ M, unsigned short* __restrict__ Eb,
    float* __restrict__ part)
{
    __shared__ unsigned short qh_l[128 * 32], ql_l[128 * 32];
    __shared__ unsigned short vh_l[128 * 32], vl_l[128 * 32];

    const int n    = blockIdx.z;
    const int tt   = blockIdx.y * 128;
    const int ts   = blockIdx.x * 128;
    const int t    = threadIdx.x;
    const int lane = t & 63;
    const int wave = t >> 6;
    const int wr   = wave >> 2;
    const int wc   = wave & 3;
    const int lr   = lane & 15;
    const int kg   = lane >> 4;

    f32x4 acc[4][2];
    #pragma unroll
    for (int i = 0; i < 4; ++i)
        #pragma unroll
        for (int j = 0; j < 2; ++j) acc[i][j] = (f32x4)0.f;

    for (int h0 = 0; h0 < HD; h0 += 32) {
        {
            const int c   = wave * 64 + lane;
            const int row = c >> 2;
            const int kb  = (c & 3) * 8;
            const int lb  = wave * 512;
            const size_t qo = ((size_t)(n * TOQ + tt + row)) * HD + h0 + kb;
            const size_t vo = ((size_t)(n * TIV + ts + row)) * HD + h0 + kb;
            gload16(QhG + qo, qh_l + lb);
            gload16(QlG + qo, ql_l + lb);
            gload16(VhG + vo, vh_l + lb);
            gload16(VlG + vo, vl_l + lb);
        }
        __syncthreads();

        s16x8 aH[4], aL[4];
        #pragma unroll
        for (int fm = 0; fm < 4; ++fm) {
            const int off = (wr * 64 + fm * 16 + lr) * 32 + kg * 8;
            aH[fm] = *(const s16x8*)(vh_l + off);
            aL[fm] = *(const s16x8*)(vl_l + off);
        }
        #pragma unroll
        for (int fn = 0; fn < 2; ++fn) {
            const int off = (wc * 32 + fn * 16 + lr) * 32 + kg * 8;
            const s16x8 bH = *(const s16x8*)(qh_l + off);
            const s16x8 bL = *(const s16x8*)(ql_l + off);
            #pragma unroll
            for (int fm = 0; fm < 4; ++fm) {
                acc[fm][fn] = __builtin_amdgcn_mfma_f32_16x16x32_bf16(aH[fm], bH, acc[fm][fn], 0, 0, 0);
                acc[fm][fn] = __builtin_amdgcn_mfma_f32_16x16x32_bf16(aH[fm], bL, acc[fm][fn], 0, 0, 0);
                acc[fm][fn] = __builtin_amdgcn_mfma_f32_16x16x32_bf16(aL[fm], bH, acc[fm][fn], 0, 0, 0);
            }
        }
        __syncthreads();
    }

    #pragma unroll
    for (int fn = 0; fn < 2; ++fn) {
        const int to_g = tt + wc * 32 + fn * 16 + lr;
        const size_t rowbase = ((size_t)n * TOQ + to_g) * TIV;
        float rs = 0.f;
        #pragma unroll
        for (int fm = 0; fm < 4; ++fm) {
            const int ti_g = ts + wr * 64 + fm * 16 + kg * 4;
            const int4 mv = *(const int4*)&M[rowbase + ti_g];
            float4 e;
            e.x = mv.x ? 0.f : __expf(acc[fm][fn][0]);
            e.y = mv.y ? 0.f : __expf(acc[fm][fn][1]);
            e.z = mv.z ? 0.f : __expf(acc[fm][fn][2]);
            e.w = mv.w ? 0.f : __expf(acc[fm][fn][3]);
            ushort4v eb;
            eb[0] = f2bf(e.x); eb[1] = f2bf(e.y);
            eb[2] = f2bf(e.z); eb[3] = f2bf(e.w);
            *(ushort4v*)&Eb[rowbase + ti_g] = eb;
            rs += (e.x + e.y) + (e.z + e.w);
        }
        rs += __shfl_xor(rs, 16, 64);
        rs += __shfl_xor(rs, 32, 64);
        if (kg == 0)
            part[((size_t)n * TOQ + to_g) * 32 + blockIdx.x * 2 + wr] = rs;
    }
}

// ---------------------------------------------------------------------------
// K1 fallback (register-staged split, f32 E).
// ---------------------------------------------------------------------------
__global__ __launch_bounds__(256) void k1_reg(
    const float* __restrict__ Q, const float* __restrict__ V,
    const int* __restrict__ M, float* __restrict__ E,
    float* __restrict__ part)
{
    __shared__ unsigned short qhi[128 * 32], qlo[128 * 32];
    __shared__ unsigned short vhi[128 * 32], vlo[128 * 32];

    const int n    = blockIdx.z;
    const int tt   = blockIdx.y * 128;
    const int ts   = blockIdx.x * 128;
    const int t    = threadIdx.x;
    const int lane = t & 63;
    const int wave = t >> 6;
    const int wr   = wave >> 1;
    const int wc   = wave & 1;
    const int lr   = lane & 15;
    const int kg   = lane >> 4;

    const float* Qb = Q + ((size_t)n * TOQ + tt) * HD;
    const float* Vb = V + ((size_t)n * TIV + ts) * HD;

    f32x4 acc[4][4];
    #pragma unroll
    for (int i = 0; i < 4; ++i)
        #pragma unroll
        for (int j = 0; j < 4; ++j) acc[i][j] = (f32x4)0.f;

    for (int h0 = 0; h0 < HD; h0 += 32) {
        #pragma unroll
        for (int it = 0; it < 2; ++it) {
            const int i   = t + it * 256;
            const int row = i >> 2;
            const int kb  = i & 3;
            const float* qs = Qb + (size_t)row * HD + h0 + kb * 8;
            const float* vs = Vb + (size_t)row * HD + h0 + kb * 8;
            const float4 q0 = *(const float4*)qs, q1 = *(const float4*)(qs + 4);
            const float4 v0 = *(const float4*)vs, v1 = *(const float4*)(vs + 4);
            ushort8v qh, ql, vh, vl;
            split8(q0, q1, qh, ql);
            split8(v0, v1, vh, vl);
            *(ushort8v*)(qhi + i * 8) = qh;
            *(ushort8v*)(qlo + i * 8) = ql;
            *(ushort8v*)(vhi + i * 8) = vh;
            *(ushort8v*)(vlo + i * 8) = vl;
        }
        __syncthreads();

        s16x8 aH[4], aL[4];
        #pragma unroll
        for (int fm = 0; fm < 4; ++fm) {
            const int off = (wr * 64 + fm * 16 + lr) * 32 + kg * 8;
            aH[fm] = *(const s16x8*)(vhi + off);
            aL[fm] = *(const s16x8*)(vlo + off);
        }
        #pragma unroll
        for (int fn = 0; fn < 4; ++fn) {
            const int off = (wc * 64 + fn * 16 + lr) * 32 + kg * 8;
            const s16x8 bH = *(const s16x8*)(qhi + off);
            const s16x8 bL = *(const s16x8*)(qlo + off);
            #pragma unroll
            for (int fm = 0; fm < 4; ++fm) {
                acc[fm][fn] = __builtin_amdgcn_mfma_f32_16x16x32_bf16(aH[fm], bH, acc[fm][fn], 0, 0, 0);
                acc[fm][fn] = __builtin_amdgcn_mfma_f32_16x16x32_bf16(aH[fm], bL, acc[fm][fn], 0, 0, 0);
                acc[fm][fn] = __builtin_amdgcn_mfma_f32_16x16x32_bf16(aL[fm], bH, acc[fm][fn], 0, 0, 0);
            }
        }
        __syncthreads();
    }

    #pragma unroll
    for (int fn = 0; fn < 4; ++fn) {
        const int to_g = tt + wc * 64 + fn * 16 + lr;
        const size_t rowbase = ((size_t)n * TOQ + to_g) * TIV;
        float rs = 0.f;
        #pragma unroll
        for (int fm = 0; fm < 4; ++fm) {
            const int ti_g = ts + wr * 64 + fm * 16 + kg * 4;
            const int4 mv = *(const int4*)&M[rowbase + ti_g];
            float4 e;
            e.x = mv.x ? 0.f : __expf(acc[fm][fn][0]);
            e.y = mv.y ? 0.f : __expf(acc[fm][fn][1]);
            e.z = mv.z ? 0.f : __expf(acc[fm][fn][2]);
            e.w = mv.w ? 0.f : __expf(acc[fm][fn][3]);
            *(float4*)&E[rowbase + ti_g] = e;
            rs += (e.x + e.y) + (e.z + e.w);
        }
        rs += __shfl_xor(rs, 16, 64);
        rs += __shfl_xor(rs, 32, 64);
        if (kg == 0)
            part[((size_t)n * TOQ + to_g) * 32 + blockIdx.x * 2 + wr] = rs;
    }
}

// ---------------------------------------------------------------------------
// K2' (tier2): rec[row] = 1/sum(part) AND stream the normalized P row.
// One wave per row; fully coalesced: 4x (16B E read -> 2x16B P write) per lane.
// ---------------------------------------------------------------------------
__global__ __launch_bounds__(256) void k2_norm(
    const float* __restrict__ part, const unsigned short* __restrict__ Eb,
    float* __restrict__ recb, float* __restrict__ P)
{
    const int row = blockIdx.x * 4 + (threadIdx.x >> 6);
    const int l   = threadIdx.x & 63;

    float s = part[(size_t)row * 32 + (l & 31)];
    #pragma unroll
    for (int off = 16; off > 0; off >>= 1) s += __shfl_xor(s, off, 32);
    const float rc = 1.f / s;
    if (l == 0) recb[row] = rc;

    const unsigned short* Erow = Eb + (size_t)row * TIV;
    float* Prow = P + (size_t)row * TIV;
    #pragma unroll
    for (int it = 0; it < 4; ++it) {
        const int col = it * 512 + l * 8;
        const ushort8v ev = *(const ushort8v*)&Erow[col];
        float4 p0, p1;
        p0.x = bf2f(ev[0]) * rc; p0.y = bf2f(ev[1]) * rc;
        p0.z = bf2f(ev[2]) * rc; p0.w = bf2f(ev[3]) * rc;
        p1.x = bf2f(ev[4]) * rc; p1.y = bf2f(ev[5]) * rc;
        p1.z = bf2f(ev[6]) * rc; p1.w = bf2f(ev[7]) * rc;
        *(float4*)&Prow[col]     = p0;
        *(float4*)&Prow[col + 4] = p1;
    }
}

// ---------------------------------------------------------------------------
// K2 fallback: rec only (from 32 partials).
// ---------------------------------------------------------------------------
__global__ __launch_bounds__(256) void k2_rowsum(
    const float* __restrict__ part, float* __restrict__ rec)
{
    const int row = blockIdx.x * 256 + threadIdx.x;
    const float4* p4 = (const float4*)(part + (size_t)row * 32);
    float s = 0.f;
    #pragma unroll
    for (int i = 0; i < 8; ++i) {
        const float4 v = p4[i];
        s += (v.x + v.y) + (v.z + v.w);
    }
    rec[row] = 1.f / s;
}

// ---------------------------------------------------------------------------
// K3' (tier2): PURE load+MFMA PV.  A-operand = raw bf16 E straight from
// memory (no scale/cvt in the loop — O is scaled by rec at the epilogue).
// 16-row tiles, 1024 blocks, 8 waves = 8 k-eighths; 3-round LDS tree reduce.
// ---------------------------------------------------------------------------
__global__ __launch_bounds__(512) void k3_o(
    const unsigned short* __restrict__ Eb, const unsigned short* __restrict__ VT,
    const float* __restrict__ recb, float* __restrict__ O)
{
    __shared__ float red[4][16][132];              // 33792 B

    const int n    = blockIdx.y;
    const int r0   = blockIdx.x * 16;
    const int t    = threadIdx.x;
    const int q    = t >> 6;                       // k-eighth 0..7
    const int lane = t & 63;
    const int lr   = lane & 15;                    // row (A) / col (B,D)
    const int kg   = lane >> 4;

    const unsigned short* Erow = Eb + ((size_t)n * TOQ + r0 + lr) * TIV;
    const unsigned short* VTb  = VT + (size_t)n * HD * TIV;

    f32x4 acc[8];
    #pragma unroll
    for (int fn = 0; fn < 8; ++fn) acc[fn] = (f32x4)0.f;

    const int kbase = q * 256 + kg * 8;

    #pragma unroll 2
    for (int k0 = 0; k0 < 256; k0 += 32) {
        const int k = kbase + k0;
        const s16x8 a = *(const s16x8*)&Erow[k];   // raw bf16 E — no VALU
        #pragma unroll
        for (int fn = 0; fn < 8; ++fn) {
            const s16x8 b = *(const s16x8*)&VTb[(size_t)(fn * 16 + lr) * TIV + k];
            acc[fn] = __builtin_amdgcn_mfma_f32_16x16x32_bf16(a, b, acc[fn], 0, 0, 0);
        }
    }

    // --- tree reduction 8 -> 4 -> 2 -> 1 ------------------------------------
    #define PARK(slot)                                                         \
        _Pragma("unroll") for (int fn = 0; fn < 8; ++fn)                       \
        _Pragma("unroll") for (int ri = 0; ri < 4; ++ri)                       \
            red[slot][kg * 4 + ri][fn * 16 + lr] = acc[fn][ri];
    #define GATHER(slot)                                                       \
        _Pragma("unroll") for (int fn = 0; fn < 8; ++fn)                       \
        _Pragma("unroll") for (int ri = 0; ri < 4; ++ri)                       \
            acc[fn][ri] += red[slot][kg * 4 + ri][fn * 16 + lr];

    if (q & 1) { PARK(q >> 1) }
    __syncthreads();
    if (!(q & 1)) { GATHER(q >> 1) }
    __syncthreads();
    if (!(q & 1) && (q & 2)) { PARK(q >> 2) }
    __syncthreads();
    if (!(q & 3)) { GATHER(q >> 2) }
    __syncthreads();
    if (q == 4) { PARK(0) }
    __syncthreads();
    if (q == 0) {
        GATHER(0)
        float rv[4];
        #pragma unroll
        for (int ri = 0; ri < 4; ++ri)
            rv[ri] = recb[(size_t)n * TOQ + r0 + kg * 4 + ri];
        #pragma unroll
        for (int fn = 0; fn < 8; ++fn) {
            #pragma unroll
            for (int ri = 0; ri < 4; ++ri) {
                const int orow = r0 + kg * 4 + ri;
                O[((size_t)n * TOQ + orow) * HD + fn * 16 + lr] = acc[fn][ri] * rv[ri];
            }
        }
    }
    #undef PARK
    #undef GATHER
}

// ---------------------------------------------------------------------------
// K3 fallback (r11 verbatim): in-place f32 E->P, 32-row tiles.
// ---------------------------------------------------------------------------
__global__ __launch_bounds__(512) void k3_pv_old(
    float* __restrict__ EP, const unsigned short* __restrict__ VT,
    const float* __restrict__ rec, float* __restrict__ O)
{
    __shared__ float red[2][3][16][132];

    const int n    = blockIdx.y;
    const int r0   = blockIdx.x * 32;
    const int t    = threadIdx.x;
    const int wave = t >> 6;
    const int lane = t & 63;
    const int p    = wave >> 2;
    const int q    = wave & 3;
    const int lr   = lane & 15;
    const int kg   = lane >> 4;

    const int rowg = r0 + p * 16 + lr;
    const float rc = rec[n * TOQ + rowg];
    float* Erow = EP + ((size_t)n * TOQ + rowg) * TIV;
    const unsigned short* VTb = VT + (size_t)n * HD * TIV;

    f32x4 acc[8];
    #pragma unroll
    for (int fn = 0; fn < 8; ++fn) acc[fn] = (f32x4)0.f;

    const int kbase = q * 512 + kg * 8;

    #pragma unroll 2
    for (int k0 = 0; k0 < 512; k0 += 32) {
        const int k = kbase + k0;
        const float4 e0 = *(const float4*)&Erow[k];
        const float4 e1 = *(const float4*)&Erow[k + 4];
        float4 p0, p1;
        p0.x = e0.x * rc; p0.y = e0.y * rc; p0.z = e0.z * rc; p0.w = e0.w * rc;
        p1.x = e1.x * rc; p1.y = e1.y * rc; p1.z = e1.z * rc; p1.w = e1.w * rc;
        *(float4*)&Erow[k]     = p0;
        *(float4*)&Erow[k + 4] = p1;

        s16x8 a;
        a[0] = (short)f2bf(p0.x); a[1] = (short)f2bf(p0.y);
        a[2] = (short)f2bf(p0.z); a[3] = (short)f2bf(p0.w);
        a[4] = (short)f2bf(p1.x); a[5] = (short)f2bf(p1.y);
        a[6] = (short)f2bf(p1.z); a[7] = (short)f2bf(p1.w);

        #pragma unroll
        for (int fn = 0; fn < 8; ++fn) {
            const s16x8 b = *(const s16x8*)&VTb[(size_t)(fn * 16 + lr) * TIV + k];
            acc[fn] = __builtin_amdgcn_mfma_f32_16x16x32_bf16(a, b, acc[fn], 0, 0, 0);
        }
    }

    if (q != 0) {
        #pragma unroll
        for (int fn = 0; fn < 8; ++fn)
            #pragma unroll
            for (int ri = 0; ri < 4; ++ri)
                red[p][q - 1][kg * 4 + ri][fn * 16 + lr] = acc[fn][ri];
    }
    __syncthreads();
    if (q == 0) {
        #pragma unroll
        for (int fn = 0; fn < 8; ++fn) {
            #pragma unroll
            for (int ri = 0; ri < 4; ++ri) {
                const int orow = r0 + p * 16 + kg * 4 + ri;
                float o = acc[fn][ri];
                o += red[p][0][kg * 4 + ri][fn * 16 + lr];
                o += red[p][1][kg * 4 + ri][fn * 16 + lr];
                o += red[p][2][kg * 4 + ri][fn * 16 + lr];
                O[((size_t)n * TOQ + orow) * HD + fn * 16 + lr] = o;
            }
        }
    }
}

// ---------------------------------------------------------------------------
extern "C" void kernel_launch(void* const* d_in, const int* in_sizes, int n_in,
                              void* d_out, int out_size, void* d_ws, size_t ws_size,
                              hipStream_t stream)
{
    const float* Q = (const float*)d_in[0];
    const float* V = (const float*)d_in[1];
    const int*   M = (const int*)d_in[2];

    float* O = (float*)d_out;                         // [8][2048][128] f32
    float* P = O + (size_t)NB * TOQ * HD;             // [8][2048][2048] f32

    char* ws = (char*)d_ws;
    const size_t partB  = (size_t)NB * TOQ * 32 * 4;      // 2 MB
    const size_t vtB    = (size_t)NB * HD * TIV * 2;      // 4 MB
    const size_t elems  = (size_t)NB * TOQ * HD;
    const size_t sbytes = elems * 2;                      // 4 MB per split array
    const size_t ebB    = (size_t)NB * TOQ * TIV * 2;     // 67 MB bf16 E

    float*          recb = (float*)ws;
    float*          part = (float*)(ws + (1 << 16));
    unsigned short* VT   = (unsigned short*)(ws + (1 << 16) + partB);
    const size_t splitOff = (1 << 16) + partB + vtB;
    const size_t ebOff    = splitOff + 4 * sbytes;
    const size_t need2    = ebOff + ebB;                  // ~89.2 MB (proven r12/r14/r15)

    k0_vt<<<dim3(TIV / 64, HD / 64, NB), 256, 0, stream>>>(V, VT);

    if (ws_size >= need2) {
        unsigned short* Qh = (unsigned short*)(ws + splitOff);
        unsigned short* Ql = (unsigned short*)(ws + splitOff + sbytes);
        unsigned short* Vh = (unsigned short*)(ws + splitOff + 2 * sbytes);
        unsigned short* Vl = (unsigned short*)(ws + splitOff + 3 * sbytes);
        unsigned short* Eb = (unsigned short*)(ws + ebOff);
        k0_split<<<dim3((unsigned)(elems / 8 / 256), 2), 256, 0, stream>>>(Q, V, Qh, Ql, Vh, Vl);
        k1_w8   <<<dim3(TIV / 128, TOQ / 128, NB), 512, 0, stream>>>(Qh, Ql, Vh, Vl, M, Eb, part);
        k2_norm <<<dim3(NB * TOQ / 4), 256, 0, stream>>>(part, Eb, recb, P);
        k3_o    <<<dim3(TOQ / 16, NB), 512, 0, stream>>>(Eb, VT, recb, O);
    } else {
        k1_reg  <<<dim3(TIV / 128, TOQ / 128, NB), 256, 0, stream>>>(Q, V, M, P, part);
        k2_rowsum<<<dim3(NB * TOQ / 256), 256, 0, stream>>>(part, recb);
        k3_pv_old<<<dim3(TOQ / 32, NB), 512, 0, stream>>>(P, VT, recb, O);
    }
}

// Round 17
// 175.540 us; speedup vs baseline: 1.1225x; 1.1225x over previous
//
#include <hip/hip_runtime.h>

#define NB  8
#define TOQ 2048
#define TIV 2048
#define HD  128

typedef float f32x4 __attribute__((ext_vector_type(4)));
typedef short s16x8 __attribute__((ext_vector_type(8)));
typedef unsigned short ushort4v __attribute__((ext_vector_type(4)));
typedef unsigned short ushort8v __attribute__((ext_vector_type(8)));

__device__ __forceinline__ unsigned short f2bf(float f) {   // RNE f32->bf16
    unsigned u = __float_as_uint(f);
    return (unsigned short)((u + 0x7FFFu + ((u >> 16) & 1u)) >> 16);
}
__device__ __forceinline__ float bf2f(unsigned short h) {
    return __uint_as_float(((unsigned)h) << 16);
}

__device__ __forceinline__ void split8(const float4 a, const float4 b,
                                       ushort8v& h, ushort8v& l) {
    const float x[8] = {a.x, a.y, a.z, a.w, b.x, b.y, b.z, b.w};
    #pragma unroll
    for (int j = 0; j < 8; ++j) {
        const unsigned short hi = f2bf(x[j]);
        h[j] = hi;
        l[j] = f2bf(x[j] - bf2f(hi));
    }
}

// async 16B global -> LDS (wave-uniform LDS base + lane*16)
__device__ __forceinline__ void gload16(const void* g, void* l) {
    __builtin_amdgcn_global_load_lds(
        (const __attribute__((address_space(1))) void*)g,
        (__attribute__((address_space(3))) void*)l, 16, 0, 0);
}

// ---------------------------------------------------------------------------
// K0a: elementwise split of Q and V into bf16 hi/lo arrays ([n][row][h]).
// ---------------------------------------------------------------------------
__global__ __launch_bounds__(256) void k0_split(
    const float* __restrict__ Q, const float* __restrict__ V,
    unsigned short* __restrict__ Qh, unsigned short* __restrict__ Ql,
    unsigned short* __restrict__ Vh, unsigned short* __restrict__ Vl)
{
    const size_t i = ((size_t)blockIdx.x * 256 + threadIdx.x) * 8;
    const float* src = blockIdx.y ? V : Q;
    unsigned short* dh = blockIdx.y ? Vh : Qh;
    unsigned short* dl = blockIdx.y ? Vl : Ql;
    const float4 a = *(const float4*)&src[i];
    const float4 b = *(const float4*)&src[i + 4];
    ushort8v h, l;
    split8(a, b, h, l);
    *(ushort8v*)&dh[i] = h;
    *(ushort8v*)&dl[i] = l;
}

// ---------------------------------------------------------------------------
// K0b: VT[n][h][s] = bf16(V[n][s][h])  (4 MB; B-fragment source for k3)
// ---------------------------------------------------------------------------
__global__ __launch_bounds__(256) void k0_vt(
    const float* __restrict__ V, unsigned short* __restrict__ VT)
{
    __shared__ unsigned short tile[64][68];
    const int n  = blockIdx.z;
    const int s0 = blockIdx.x * 64;
    const int h0 = blockIdx.y * 64;
    const int t  = threadIdx.x;

    #pragma unroll
    for (int it = 0; it < 4; ++it) {
        const int f = t + it * 256;
        const int r = f >> 4;
        const int c = f & 15;
        const float4 v = *(const float4*)&V[((size_t)(n * TIV + s0 + r)) * HD + h0 + 4 * c];
        tile[4 * c + 0][r] = f2bf(v.x);
        tile[4 * c + 1][r] = f2bf(v.y);
        tile[4 * c + 2][r] = f2bf(v.z);
        tile[4 * c + 3][r] = f2bf(v.w);
    }
    __syncthreads();

    #pragma unroll
    for (int it = 0; it < 2; ++it) {
        const int f  = t + it * 256;
        const int hh = f >> 3;
        const int sc = f & 7;
        ushort8v o;
        #pragma unroll
        for (int j = 0; j < 8; ++j) o[j] = tile[hh][8 * sc + j];
        *(ushort8v*)&VT[((size_t)(n * HD + h0 + hh)) * TIV + s0 + 8 * sc] = o;
    }
}

// ---------------------------------------------------------------------------
// K1 (tier2, r14/r15-verified): 8-wave transposed QK^T (A=V,B=Q), acc[4][2],
// global_load_lds staging of pre-split arrays, bf16 E out, fused partials.
// ---------------------------------------------------------------------------
__global__ __launch_bounds__(512) void k1_w8(
    const unsigned short* __restrict__ QhG, const unsigned short* __restrict__ QlG,
    const unsigned short* __restrict__ VhG, const unsigned short* __restrict__ VlG,
    const int* __restrict__ M, unsigned short* __restrict__ Eb,
    float* __restrict__ part)
{
    __shared__ unsigned short qh_l[128 * 32], ql_l[128 * 32];
    __shared__ unsigned short vh_l[128 * 32], vl_l[128 * 32];

    const int n    = blockIdx.z;
    const int tt   = blockIdx.y * 128;
    const int ts   = blockIdx.x * 128;
    const int t    = threadIdx.x;
    const int lane = t & 63;
    const int wave = t >> 6;
    const int wr   = wave >> 2;
    const int wc   = wave & 3;
    const int lr   = lane & 15;
    const int kg   = lane >> 4;

    f32x4 acc[4][2];
    #pragma unroll
    for (int i = 0; i < 4; ++i)
        #pragma unroll
        for (int j = 0; j < 2; ++j) acc[i][j] = (f32x4)0.f;

    for (int h0 = 0; h0 < HD; h0 += 32) {
        {
            const int c   = wave * 64 + lane;
            const int row = c >> 2;
            const int kb  = (c & 3) * 8;
            const int lb  = wave * 512;
            const size_t qo = ((size_t)(n * TOQ + tt + row)) * HD + h0 + kb;
            const size_t vo = ((size_t)(n * TIV + ts + row)) * HD + h0 + kb;
            gload16(QhG + qo, qh_l + lb);
            gload16(QlG + qo, ql_l + lb);
            gload16(VhG + vo, vh_l + lb);
            gload16(VlG + vo, vl_l + lb);
        }
        __syncthreads();

        s16x8 aH[4], aL[4];
        #pragma unroll
        for (int fm = 0; fm < 4; ++fm) {
            const int off = (wr * 64 + fm * 16 + lr) * 32 + kg * 8;
            aH[fm] = *(const s16x8*)(vh_l + off);
            aL[fm] = *(const s16x8*)(vl_l + off);
        }
        #pragma unroll
        for (int fn = 0; fn < 2; ++fn) {
            const int off = (wc * 32 + fn * 16 + lr) * 32 + kg * 8;
            const s16x8 bH = *(const s16x8*)(qh_l + off);
            const s16x8 bL = *(const s16x8*)(ql_l + off);
            #pragma unroll
            for (int fm = 0; fm < 4; ++fm) {
                acc[fm][fn] = __builtin_amdgcn_mfma_f32_16x16x32_bf16(aH[fm], bH, acc[fm][fn], 0, 0, 0);
                acc[fm][fn] = __builtin_amdgcn_mfma_f32_16x16x32_bf16(aH[fm], bL, acc[fm][fn], 0, 0, 0);
                acc[fm][fn] = __builtin_amdgcn_mfma_f32_16x16x32_bf16(aL[fm], bH, acc[fm][fn], 0, 0, 0);
            }
        }
        __syncthreads();
    }

    #pragma unroll
    for (int fn = 0; fn < 2; ++fn) {
        const int to_g = tt + wc * 32 + fn * 16 + lr;
        const size_t rowbase = ((size_t)n * TOQ + to_g) * TIV;
        float rs = 0.f;
        #pragma unroll
        for (int fm = 0; fm < 4; ++fm) {
            const int ti_g = ts + wr * 64 + fm * 16 + kg * 4;
            const int4 mv = *(const int4*)&M[rowbase + ti_g];
            float4 e;
            e.x = mv.x ? 0.f : __expf(acc[fm][fn][0]);
            e.y = mv.y ? 0.f : __expf(acc[fm][fn][1]);
            e.z = mv.z ? 0.f : __expf(acc[fm][fn][2]);
            e.w = mv.w ? 0.f : __expf(acc[fm][fn][3]);
            ushort4v eb;
            eb[0] = f2bf(e.x); eb[1] = f2bf(e.y);
            eb[2] = f2bf(e.z); eb[3] = f2bf(e.w);
            *(ushort4v*)&Eb[rowbase + ti_g] = eb;
            rs += (e.x + e.y) + (e.z + e.w);
        }
        rs += __shfl_xor(rs, 16, 64);
        rs += __shfl_xor(rs, 32, 64);
        if (kg == 0)
            part[((size_t)n * TOQ + to_g) * 32 + blockIdx.x * 2 + wr] = rs;
    }
}

// ---------------------------------------------------------------------------
// K1 fallback (register-staged split, f32 E).
// ---------------------------------------------------------------------------
__global__ __launch_bounds__(256) void k1_reg(
    const float* __restrict__ Q, const float* __restrict__ V,
    const int* __restrict__ M, float* __restrict__ E,
    float* __restrict__ part)
{
    __shared__ unsigned short qhi[128 * 32], qlo[128 * 32];
    __shared__ unsigned short vhi[128 * 32], vlo[128 * 32];

    const int n    = blockIdx.z;
    const int tt   = blockIdx.y * 128;
    const int ts   = blockIdx.x * 128;
    const int t    = threadIdx.x;
    const int lane = t & 63;
    const int wave = t >> 6;
    const int wr   = wave >> 1;
    const int wc   = wave & 1;
    const int lr   = lane & 15;
    const int kg   = lane >> 4;

    const float* Qb = Q + ((size_t)n * TOQ + tt) * HD;
    const float* Vb = V + ((size_t)n * TIV + ts) * HD;

    f32x4 acc[4][4];
    #pragma unroll
    for (int i = 0; i < 4; ++i)
        #pragma unroll
        for (int j = 0; j < 4; ++j) acc[i][j] = (f32x4)0.f;

    for (int h0 = 0; h0 < HD; h0 += 32) {
        #pragma unroll
        for (int it = 0; it < 2; ++it) {
            const int i   = t + it * 256;
            const int row = i >> 2;
            const int kb  = i & 3;
            const float* qs = Qb + (size_t)row * HD + h0 + kb * 8;
            const float* vs = Vb + (size_t)row * HD + h0 + kb * 8;
            const float4 q0 = *(const float4*)qs, q1 = *(const float4*)(qs + 4);
            const float4 v0 = *(const float4*)vs, v1 = *(const float4*)(vs + 4);
            ushort8v qh, ql, vh, vl;
            split8(q0, q1, qh, ql);
            split8(v0, v1, vh, vl);
            *(ushort8v*)(qhi + i * 8) = qh;
            *(ushort8v*)(qlo + i * 8) = ql;
            *(ushort8v*)(vhi + i * 8) = vh;
            *(ushort8v*)(vlo + i * 8) = vl;
        }
        __syncthreads();

        s16x8 aH[4], aL[4];
        #pragma unroll
        for (int fm = 0; fm < 4; ++fm) {
            const int off = (wr * 64 + fm * 16 + lr) * 32 + kg * 8;
            aH[fm] = *(const s16x8*)(vhi + off);
            aL[fm] = *(const s16x8*)(vlo + off);
        }
        #pragma unroll
        for (int fn = 0; fn < 4; ++fn) {
            const int off = (wc * 64 + fn * 16 + lr) * 32 + kg * 8;
            const s16x8 bH = *(const s16x8*)(qhi + off);
            const s16x8 bL = *(const s16x8*)(qlo + off);
            #pragma unroll
            for (int fm = 0; fm < 4; ++fm) {
                acc[fm][fn] = __builtin_amdgcn_mfma_f32_16x16x32_bf16(aH[fm], bH, acc[fm][fn], 0, 0, 0);
                acc[fm][fn] = __builtin_amdgcn_mfma_f32_16x16x32_bf16(aH[fm], bL, acc[fm][fn], 0, 0, 0);
                acc[fm][fn] = __builtin_amdgcn_mfma_f32_16x16x32_bf16(aL[fm], bH, acc[fm][fn], 0, 0, 0);
            }
        }
        __syncthreads();
    }

    #pragma unroll
    for (int fn = 0; fn < 4; ++fn) {
        const int to_g = tt + wc * 64 + fn * 16 + lr;
        const size_t rowbase = ((size_t)n * TOQ + to_g) * TIV;
        float rs = 0.f;
        #pragma unroll
        for (int fm = 0; fm < 4; ++fm) {
            const int ti_g = ts + wr * 64 + fm * 16 + kg * 4;
            const int4 mv = *(const int4*)&M[rowbase + ti_g];
            float4 e;
            e.x = mv.x ? 0.f : __expf(acc[fm][fn][0]);
            e.y = mv.y ? 0.f : __expf(acc[fm][fn][1]);
            e.z = mv.z ? 0.f : __expf(acc[fm][fn][2]);
            e.w = mv.w ? 0.f : __expf(acc[fm][fn][3]);
            *(float4*)&E[rowbase + ti_g] = e;
            rs += (e.x + e.y) + (e.z + e.w);
        }
        rs += __shfl_xor(rs, 16, 64);
        rs += __shfl_xor(rs, 32, 64);
        if (kg == 0)
            part[((size_t)n * TOQ + to_g) * 32 + blockIdx.x * 2 + wr] = rs;
    }
}

// ---------------------------------------------------------------------------
// K2: rec[row] = 1 / sum of 32 partials
// ---------------------------------------------------------------------------
__global__ __launch_bounds__(256) void k2_rowsum(
    const float* __restrict__ part, float* __restrict__ rec)
{
    const int row = blockIdx.x * 256 + threadIdx.x;
    const float4* p4 = (const float4*)(part + (size_t)row * 32);
    float s = 0.f;
    #pragma unroll
    for (int i = 0; i < 8; ++i) {
        const float4 v = p4[i];
        s += (v.x + v.y) + (v.z + v.w);
    }
    rec[row] = 1.f / s;
}

// ---------------------------------------------------------------------------
// K3 (tier2, r15-verified best): MAX-OCCUPANCY PV. 16-row tiles -> 1024
// blocks; 8 waves = 8 k-eighths of the same 16 rows; bf16 E, scattered VT
// gathers, fire-and-forget f32 P; 3-round LDS tree reduction (33.8 KB).
// ---------------------------------------------------------------------------
__global__ __launch_bounds__(512) void k3_occ(
    const unsigned short* __restrict__ Eb, const unsigned short* __restrict__ VT,
    const float* __restrict__ rec, float* __restrict__ P, float* __restrict__ O)
{
    __shared__ float red[4][16][132];              // 33792 B

    const int n    = blockIdx.y;
    const int r0   = blockIdx.x * 16;
    const int t    = threadIdx.x;
    const int q    = t >> 6;                       // k-eighth 0..7
    const int lane = t & 63;
    const int lr   = lane & 15;                    // row (A) / col (B,D)
    const int kg   = lane >> 4;

    const int rowg = r0 + lr;
    const float rc = rec[n * TOQ + rowg];
    const unsigned short* Erow = Eb + ((size_t)n * TOQ + rowg) * TIV;
    float* Prow = P + ((size_t)n * TOQ + rowg) * TIV;
    const unsigned short* VTb = VT + (size_t)n * HD * TIV;

    f32x4 acc[8];
    #pragma unroll
    for (int fn = 0; fn < 8; ++fn) acc[fn] = (f32x4)0.f;

    const int kbase = q * 256 + kg * 8;

    #pragma unroll 2
    for (int k0 = 0; k0 < 256; k0 += 32) {
        const int k = kbase + k0;
        const ushort8v ev = *(const ushort8v*)&Erow[k];
        float pv[8];
        #pragma unroll
        for (int j = 0; j < 8; ++j) pv[j] = bf2f(ev[j]) * rc;

        float4 p0, p1;
        p0.x = pv[0]; p0.y = pv[1]; p0.z = pv[2]; p0.w = pv[3];
        p1.x = pv[4]; p1.y = pv[5]; p1.z = pv[6]; p1.w = pv[7];
        *(float4*)&Prow[k]     = p0;               // P output (disjoint buffer)
        *(float4*)&Prow[k + 4] = p1;

        s16x8 a;
        #pragma unroll
        for (int j = 0; j < 8; ++j) a[j] = (short)f2bf(pv[j]);

        #pragma unroll
        for (int fn = 0; fn < 8; ++fn) {
            const s16x8 b = *(const s16x8*)&VTb[(size_t)(fn * 16 + lr) * TIV + k];
            acc[fn] = __builtin_amdgcn_mfma_f32_16x16x32_bf16(a, b, acc[fn], 0, 0, 0);
        }
    }

    // --- tree reduction 8 -> 4 -> 2 -> 1 ------------------------------------
    #define PARK(slot)                                                         \
        _Pragma("unroll") for (int fn = 0; fn < 8; ++fn)                       \
        _Pragma("unroll") for (int ri = 0; ri < 4; ++ri)                       \
            red[slot][kg * 4 + ri][fn * 16 + lr] = acc[fn][ri];
    #define GATHER(slot)                                                       \
        _Pragma("unroll") for (int fn = 0; fn < 8; ++fn)                       \
        _Pragma("unroll") for (int ri = 0; ri < 4; ++ri)                       \
            acc[fn][ri] += red[slot][kg * 4 + ri][fn * 16 + lr];

    if (q & 1) { PARK(q >> 1) }                    // 1,3,5,7 -> slots 0..3
    __syncthreads();
    if (!(q & 1)) { GATHER(q >> 1) }               // 0,2,4,6 add
    __syncthreads();
    if (!(q & 1) && (q & 2)) { PARK(q >> 2) }      // 2,6 -> slots 0,1
    __syncthreads();
    if (!(q & 3)) { GATHER(q >> 2) }               // 0,4 add
    __syncthreads();
    if (q == 4) { PARK(0) }                        // 4 -> slot 0
    __syncthreads();
    if (q == 0) {
        GATHER(0)
        #pragma unroll
        for (int fn = 0; fn < 8; ++fn) {
            #pragma unroll
            for (int ri = 0; ri < 4; ++ri) {
                const int orow = r0 + kg * 4 + ri;
                O[((size_t)n * TOQ + orow) * HD + fn * 16 + lr] = acc[fn][ri];
            }
        }
    }
    #undef PARK
    #undef GATHER
}

// ---------------------------------------------------------------------------
// K3 fallback (r11 verbatim): in-place f32 E->P, 32-row tiles.
// ---------------------------------------------------------------------------
__global__ __launch_bounds__(512) void k3_pv_old(
    float* __restrict__ EP, const unsigned short* __restrict__ VT,
    const float* __restrict__ rec, float* __restrict__ O)
{
    __shared__ float red[2][3][16][132];

    const int n    = blockIdx.y;
    const int r0   = blockIdx.x * 32;
    const int t    = threadIdx.x;
    const int wave = t >> 6;
    const int lane = t & 63;
    const int p    = wave >> 2;
    const int q    = wave & 3;
    const int lr   = lane & 15;
    const int kg   = lane >> 4;

    const int rowg = r0 + p * 16 + lr;
    const float rc = rec[n * TOQ + rowg];
    float* Erow = EP + ((size_t)n * TOQ + rowg) * TIV;
    const unsigned short* VTb = VT + (size_t)n * HD * TIV;

    f32x4 acc[8];
    #pragma unroll
    for (int fn = 0; fn < 8; ++fn) acc[fn] = (f32x4)0.f;

    const int kbase = q * 512 + kg * 8;

    #pragma unroll 2
    for (int k0 = 0; k0 < 512; k0 += 32) {
        const int k = kbase + k0;
        const float4 e0 = *(const float4*)&Erow[k];
        const float4 e1 = *(const float4*)&Erow[k + 4];
        float4 p0, p1;
        p0.x = e0.x * rc; p0.y = e0.y * rc; p0.z = e0.z * rc; p0.w = e0.w * rc;
        p1.x = e1.x * rc; p1.y = e1.y * rc; p1.z = e1.z * rc; p1.w = e1.w * rc;
        *(float4*)&Erow[k]     = p0;
        *(float4*)&Erow[k + 4] = p1;

        s16x8 a;
        a[0] = (short)f2bf(p0.x); a[1] = (short)f2bf(p0.y);
        a[2] = (short)f2bf(p0.z); a[3] = (short)f2bf(p0.w);
        a[4] = (short)f2bf(p1.x); a[5] = (short)f2bf(p1.y);
        a[6] = (short)f2bf(p1.z); a[7] = (short)f2bf(p1.w);

        #pragma unroll
        for (int fn = 0; fn < 8; ++fn) {
            const s16x8 b = *(const s16x8*)&VTb[(size_t)(fn * 16 + lr) * TIV + k];
            acc[fn] = __builtin_amdgcn_mfma_f32_16x16x32_bf16(a, b, acc[fn], 0, 0, 0);
        }
    }

    if (q != 0) {
        #pragma unroll
        for (int fn = 0; fn < 8; ++fn)
            #pragma unroll
            for (int ri = 0; ri < 4; ++ri)
                red[p][q - 1][kg * 4 + ri][fn * 16 + lr] = acc[fn][ri];
    }
    __syncthreads();
    if (q == 0) {
        #pragma unroll
        for (int fn = 0; fn < 8; ++fn) {
            #pragma unroll
            for (int ri = 0; ri < 4; ++ri) {
                const int orow = r0 + p * 16 + kg * 4 + ri;
                float o = acc[fn][ri];
                o += red[p][0][kg * 4 + ri][fn * 16 + lr];
                o += red[p][1][kg * 4 + ri][fn * 16 + lr];
                o += red[p][2][kg * 4 + ri][fn * 16 + lr];
                O[((size_t)n * TOQ + orow) * HD + fn * 16 + lr] = o;
            }
        }
    }
}

// ---------------------------------------------------------------------------
extern "C" void kernel_launch(void* const* d_in, const int* in_sizes, int n_in,
                              void* d_out, int out_size, void* d_ws, size_t ws_size,
                              hipStream_t stream)
{
    const float* Q = (const float*)d_in[0];
    const float* V = (const float*)d_in[1];
    const int*   M = (const int*)d_in[2];

    float* O = (float*)d_out;                         // [8][2048][128] f32
    float* P = O + (size_t)NB * TOQ * HD;             // [8][2048][2048] f32

    char* ws = (char*)d_ws;
    const size_t partB  = (size_t)NB * TOQ * 32 * 4;      // 2 MB
    const size_t vtB    = (size_t)NB * HD * TIV * 2;      // 4 MB
    const size_t elems  = (size_t)NB * TOQ * HD;
    const size_t sbytes = elems * 2;                      // 4 MB per split array
    const size_t ebB    = (size_t)NB * TOQ * TIV * 2;     // 67 MB bf16 E

    float*          recb = (float*)ws;
    float*          part = (float*)(ws + (1 << 16));
    unsigned short* VT   = (unsigned short*)(ws + (1 << 16) + partB);
    const size_t splitOff = (1 << 16) + partB + vtB;
    const size_t ebOff    = splitOff + 4 * sbytes;
    const size_t need2    = ebOff + ebB;                  // ~89.2 MB (proven r12/r14/r15)

    k0_vt<<<dim3(TIV / 64, HD / 64, NB), 256, 0, stream>>>(V, VT);

    if (ws_size >= need2) {
        unsigned short* Qh = (unsigned short*)(ws + splitOff);
        unsigned short* Ql = (unsigned short*)(ws + splitOff + sbytes);
        unsigned short* Vh = (unsigned short*)(ws + splitOff + 2 * sbytes);
        unsigned short* Vl = (unsigned short*)(ws + splitOff + 3 * sbytes);
        unsigned short* Eb = (unsigned short*)(ws + ebOff);
        k0_split<<<dim3((unsigned)(elems / 8 / 256), 2), 256, 0, stream>>>(Q, V, Qh, Ql, Vh, Vl);
        k1_w8   <<<dim3(TIV / 128, TOQ / 128, NB), 512, 0, stream>>>(Qh, Ql, Vh, Vl, M, Eb, part);
        k2_rowsum<<<dim3(NB * TOQ / 256), 256, 0, stream>>>(part, recb);
        k3_occ  <<<dim3(TOQ / 16, NB), 512, 0, stream>>>(Eb, VT, recb, P, O);
    } else {
        k1_reg  <<<dim3(TIV / 128, TOQ / 128, NB), 256, 0, stream>>>(Q, V, M, P, part);
        k2_rowsum<<<dim3(NB * TOQ / 256), 256, 0, stream>>>(part, recb);
        k3_pv_old<<<dim3(TOQ / 32, NB), 512, 0, stream>>>(P, VT, recb, O);
    }
}

// Round 18
// 164.977 us; speedup vs baseline: 1.1944x; 1.0640x over previous
//
#include <hip/hip_runtime.h>

#define NB  8
#define TOQ 2048
#define TIV 2048
#define HD  128

typedef float f32x4 __attribute__((ext_vector_type(4)));
typedef short s16x8 __attribute__((ext_vector_type(8)));
typedef unsigned short ushort4v __attribute__((ext_vector_type(4)));
typedef unsigned short ushort8v __attribute__((ext_vector_type(8)));

__device__ __forceinline__ unsigned short f2bf(float f) {   // RNE f32->bf16
    unsigned u = __float_as_uint(f);
    return (unsigned short)((u + 0x7FFFu + ((u >> 16) & 1u)) >> 16);
}
__device__ __forceinline__ float bf2f(unsigned short h) {
    return __uint_as_float(((unsigned)h) << 16);
}

__device__ __forceinline__ void split8(const float4 a, const float4 b,
                                       ushort8v& h, ushort8v& l) {
    const float x[8] = {a.x, a.y, a.z, a.w, b.x, b.y, b.z, b.w};
    #pragma unroll
    for (int j = 0; j < 8; ++j) {
        const unsigned short hi = f2bf(x[j]);
        h[j] = hi;
        l[j] = f2bf(x[j] - bf2f(hi));
    }
}

// async 16B global -> LDS (wave-uniform LDS base + lane*16)
__device__ __forceinline__ void gload16(const void* g, void* l) {
    __builtin_amdgcn_global_load_lds(
        (const __attribute__((address_space(1))) void*)g,
        (__attribute__((address_space(3))) void*)l, 16, 0, 0);
}

// ---------------------------------------------------------------------------
// K0a: elementwise split of Q and V into bf16 hi/lo arrays ([n][row][h]).
// ---------------------------------------------------------------------------
__global__ __launch_bounds__(256) void k0_split(
    const float* __restrict__ Q, const float* __restrict__ V,
    unsigned short* __restrict__ Qh, unsigned short* __restrict__ Ql,
    unsigned short* __restrict__ Vh, unsigned short* __restrict__ Vl)
{
    const size_t i = ((size_t)blockIdx.x * 256 + threadIdx.x) * 8;
    const float* src = blockIdx.y ? V : Q;
    unsigned short* dh = blockIdx.y ? Vh : Qh;
    unsigned short* dl = blockIdx.y ? Vl : Ql;
    const float4 a = *(const float4*)&src[i];
    const float4 b = *(const float4*)&src[i + 4];
    ushort8v h, l;
    split8(a, b, h, l);
    *(ushort8v*)&dh[i] = h;
    *(ushort8v*)&dl[i] = l;
}

// ---------------------------------------------------------------------------
// K0b: VT[n][h][s] = bf16(V[n][s][h])  (4 MB; B-fragment source for k3)
// ---------------------------------------------------------------------------
__global__ __launch_bounds__(256) void k0_vt(
    const float* __restrict__ V, unsigned short* __restrict__ VT)
{
    __shared__ unsigned short tile[64][68];
    const int n  = blockIdx.z;
    const int s0 = blockIdx.x * 64;
    const int h0 = blockIdx.y * 64;
    const int t  = threadIdx.x;

    #pragma unroll
    for (int it = 0; it < 4; ++it) {
        const int f = t + it * 256;
        const int r = f >> 4;
        const int c = f & 15;
        const float4 v = *(const float4*)&V[((size_t)(n * TIV + s0 + r)) * HD + h0 + 4 * c];
        tile[4 * c + 0][r] = f2bf(v.x);
        tile[4 * c + 1][r] = f2bf(v.y);
        tile[4 * c + 2][r] = f2bf(v.z);
        tile[4 * c + 3][r] = f2bf(v.w);
    }
    __syncthreads();

    #pragma unroll
    for (int it = 0; it < 2; ++it) {
        const int f  = t + it * 256;
        const int hh = f >> 3;
        const int sc = f & 7;
        ushort8v o;
        #pragma unroll
        for (int j = 0; j < 8; ++j) o[j] = tile[hh][8 * sc + j];
        *(ushort8v*)&VT[((size_t)(n * HD + h0 + hh)) * TIV + s0 + 8 * sc] = o;
    }
}

// ---------------------------------------------------------------------------
// K1 (tier2): 8-wave transposed QK^T (A=V,B=Q), acc[4][2], global_load_lds
// staging, bf16 E out, fused partials.  XCD-SWIZZLED 1D grid: n = bid & 7 so
// round-robin dispatch pins each batch to one XCD (split arrays L2-local).
// ---------------------------------------------------------------------------
__global__ __launch_bounds__(512) void k1_w8(
    const unsigned short* __restrict__ QhG, const unsigned short* __restrict__ QlG,
    const unsigned short* __restrict__ VhG, const unsigned short* __restrict__ VlG,
    const int* __restrict__ M, unsigned short* __restrict__ Eb,
    float* __restrict__ part)
{
    __shared__ unsigned short qh_l[128 * 32], ql_l[128 * 32];
    __shared__ unsigned short vh_l[128 * 32], vl_l[128 * 32];

    const int bid  = blockIdx.x;
    const int n    = bid & 7;            // XCD-local batch
    const int xy   = bid >> 3;
    const int bx   = xy & 15;            // ti tile
    const int by   = xy >> 4;            // to tile
    const int tt   = by * 128;
    const int ts   = bx * 128;
    const int t    = threadIdx.x;
    const int lane = t & 63;
    const int wave = t >> 6;
    const int wr   = wave >> 2;
    const int wc   = wave & 3;
    const int lr   = lane & 15;
    const int kg   = lane >> 4;

    f32x4 acc[4][2];
    #pragma unroll
    for (int i = 0; i < 4; ++i)
        #pragma unroll
        for (int j = 0; j < 2; ++j) acc[i][j] = (f32x4)0.f;

    for (int h0 = 0; h0 < HD; h0 += 32) {
        {
            const int c   = wave * 64 + lane;
            const int row = c >> 2;
            const int kb  = (c & 3) * 8;
            const int lb  = wave * 512;
            const size_t qo = ((size_t)(n * TOQ + tt + row)) * HD + h0 + kb;
            const size_t vo = ((size_t)(n * TIV + ts + row)) * HD + h0 + kb;
            gload16(QhG + qo, qh_l + lb);
            gload16(QlG + qo, ql_l + lb);
            gload16(VhG + vo, vh_l + lb);
            gload16(VlG + vo, vl_l + lb);
        }
        __syncthreads();

        s16x8 aH[4], aL[4];
        #pragma unroll
        for (int fm = 0; fm < 4; ++fm) {
            const int off = (wr * 64 + fm * 16 + lr) * 32 + kg * 8;
            aH[fm] = *(const s16x8*)(vh_l + off);
            aL[fm] = *(const s16x8*)(vl_l + off);
        }
        #pragma unroll
        for (int fn = 0; fn < 2; ++fn) {
            const int off = (wc * 32 + fn * 16 + lr) * 32 + kg * 8;
            const s16x8 bH = *(const s16x8*)(qh_l + off);
            const s16x8 bL = *(const s16x8*)(ql_l + off);
            #pragma unroll
            for (int fm = 0; fm < 4; ++fm) {
                acc[fm][fn] = __builtin_amdgcn_mfma_f32_16x16x32_bf16(aH[fm], bH, acc[fm][fn], 0, 0, 0);
                acc[fm][fn] = __builtin_amdgcn_mfma_f32_16x16x32_bf16(aH[fm], bL, acc[fm][fn], 0, 0, 0);
                acc[fm][fn] = __builtin_amdgcn_mfma_f32_16x16x32_bf16(aL[fm], bH, acc[fm][fn], 0, 0, 0);
            }
        }
        __syncthreads();
    }

    #pragma unroll
    for (int fn = 0; fn < 2; ++fn) {
        const int to_g = tt + wc * 32 + fn * 16 + lr;
        const size_t rowbase = ((size_t)n * TOQ + to_g) * TIV;
        float rs = 0.f;
        #pragma unroll
        for (int fm = 0; fm < 4; ++fm) {
            const int ti_g = ts + wr * 64 + fm * 16 + kg * 4;
            const int4 mv = *(const int4*)&M[rowbase + ti_g];
            float4 e;
            e.x = mv.x ? 0.f : __expf(acc[fm][fn][0]);
            e.y = mv.y ? 0.f : __expf(acc[fm][fn][1]);
            e.z = mv.z ? 0.f : __expf(acc[fm][fn][2]);
            e.w = mv.w ? 0.f : __expf(acc[fm][fn][3]);
            ushort4v eb;
            eb[0] = f2bf(e.x); eb[1] = f2bf(e.y);
            eb[2] = f2bf(e.z); eb[3] = f2bf(e.w);
            *(ushort4v*)&Eb[rowbase + ti_g] = eb;
            rs += (e.x + e.y) + (e.z + e.w);
        }
        rs += __shfl_xor(rs, 16, 64);
        rs += __shfl_xor(rs, 32, 64);
        if (kg == 0)
            part[((size_t)n * TOQ + to_g) * 32 + bx * 2 + wr] = rs;
    }
}

// ---------------------------------------------------------------------------
// K1 fallback (register-staged split, f32 E).
// ---------------------------------------------------------------------------
__global__ __launch_bounds__(256) void k1_reg(
    const float* __restrict__ Q, const float* __restrict__ V,
    const int* __restrict__ M, float* __restrict__ E,
    float* __restrict__ part)
{
    __shared__ unsigned short qhi[128 * 32], qlo[128 * 32];
    __shared__ unsigned short vhi[128 * 32], vlo[128 * 32];

    const int n    = blockIdx.z;
    const int tt   = blockIdx.y * 128;
    const int ts   = blockIdx.x * 128;
    const int t    = threadIdx.x;
    const int lane = t & 63;
    const int wave = t >> 6;
    const int wr   = wave >> 1;
    const int wc   = wave & 1;
    const int lr   = lane & 15;
    const int kg   = lane >> 4;

    const float* Qb = Q + ((size_t)n * TOQ + tt) * HD;
    const float* Vb = V + ((size_t)n * TIV + ts) * HD;

    f32x4 acc[4][4];
    #pragma unroll
    for (int i = 0; i < 4; ++i)
        #pragma unroll
        for (int j = 0; j < 4; ++j) acc[i][j] = (f32x4)0.f;

    for (int h0 = 0; h0 < HD; h0 += 32) {
        #pragma unroll
        for (int it = 0; it < 2; ++it) {
            const int i   = t + it * 256;
            const int row = i >> 2;
            const int kb  = i & 3;
            const float* qs = Qb + (size_t)row * HD + h0 + kb * 8;
            const float* vs = Vb + (size_t)row * HD + h0 + kb * 8;
            const float4 q0 = *(const float4*)qs, q1 = *(const float4*)(qs + 4);
            const float4 v0 = *(const float4*)vs, v1 = *(const float4*)(vs + 4);
            ushort8v qh, ql, vh, vl;
            split8(q0, q1, qh, ql);
            split8(v0, v1, vh, vl);
            *(ushort8v*)(qhi + i * 8) = qh;
            *(ushort8v*)(qlo + i * 8) = ql;
            *(ushort8v*)(vhi + i * 8) = vh;
            *(ushort8v*)(vlo + i * 8) = vl;
        }
        __syncthreads();

        s16x8 aH[4], aL[4];
        #pragma unroll
        for (int fm = 0; fm < 4; ++fm) {
            const int off = (wr * 64 + fm * 16 + lr) * 32 + kg * 8;
            aH[fm] = *(const s16x8*)(vhi + off);
            aL[fm] = *(const s16x8*)(vlo + off);
        }
        #pragma unroll
        for (int fn = 0; fn < 4; ++fn) {
            const int off = (wc * 64 + fn * 16 + lr) * 32 + kg * 8;
            const s16x8 bH = *(const s16x8*)(qhi + off);
            const s16x8 bL = *(const s16x8*)(qlo + off);
            #pragma unroll
            for (int fm = 0; fm < 4; ++fm) {
                acc[fm][fn] = __builtin_amdgcn_mfma_f32_16x16x32_bf16(aH[fm], bH, acc[fm][fn], 0, 0, 0);
                acc[fm][fn] = __builtin_amdgcn_mfma_f32_16x16x32_bf16(aH[fm], bL, acc[fm][fn], 0, 0, 0);
                acc[fm][fn] = __builtin_amdgcn_mfma_f32_16x16x32_bf16(aL[fm], bH, acc[fm][fn], 0, 0, 0);
            }
        }
        __syncthreads();
    }

    #pragma unroll
    for (int fn = 0; fn < 4; ++fn) {
        const int to_g = tt + wc * 64 + fn * 16 + lr;
        const size_t rowbase = ((size_t)n * TOQ + to_g) * TIV;
        float rs = 0.f;
        #pragma unroll
        for (int fm = 0; fm < 4; ++fm) {
            const int ti_g = ts + wr * 64 + fm * 16 + kg * 4;
            const int4 mv = *(const int4*)&M[rowbase + ti_g];
            float4 e;
            e.x = mv.x ? 0.f : __expf(acc[fm][fn][0]);
            e.y = mv.y ? 0.f : __expf(acc[fm][fn][1]);
            e.z = mv.z ? 0.f : __expf(acc[fm][fn][2]);
            e.w = mv.w ? 0.f : __expf(acc[fm][fn][3]);
            *(float4*)&E[rowbase + ti_g] = e;
            rs += (e.x + e.y) + (e.z + e.w);
        }
        rs += __shfl_xor(rs, 16, 64);
        rs += __shfl_xor(rs, 32, 64);
        if (kg == 0)
            part[((size_t)n * TOQ + to_g) * 32 + blockIdx.x * 2 + wr] = rs;
    }
}

// ---------------------------------------------------------------------------
// K2: rec[row] = 1 / sum of 32 partials
// ---------------------------------------------------------------------------
__global__ __launch_bounds__(256) void k2_rowsum(
    const float* __restrict__ part, float* __restrict__ rec)
{
    const int row = blockIdx.x * 256 + threadIdx.x;
    const float4* p4 = (const float4*)(part + (size_t)row * 32);
    float s = 0.f;
    #pragma unroll
    for (int i = 0; i < 8; ++i) {
        const float4 v = p4[i];
        s += (v.x + v.y) + (v.z + v.w);
    }
    rec[row] = 1.f / s;
}

// ---------------------------------------------------------------------------
// K3 (tier2): MAX-OCCUPANCY PV, XCD-SWIZZLED 1D grid (n = bid & 7 -> each
// XCD serves one batch; its 512KB VT slice becomes L2-resident).
// 16-row tiles; 8 waves = 8 k-eighths; 3-round LDS tree reduction.
// ---------------------------------------------------------------------------
__global__ __launch_bounds__(512) void k3_occ(
    const unsigned short* __restrict__ Eb, const unsigned short* __restrict__ VT,
    const float* __restrict__ rec, float* __restrict__ P, float* __restrict__ O)
{
    __shared__ float red[4][16][132];              // 33792 B

    const int bid  = blockIdx.x;
    const int n    = bid & 7;                      // XCD-local batch
    const int r0   = (bid >> 3) * 16;
    const int t    = threadIdx.x;
    const int q    = t >> 6;                       // k-eighth 0..7
    const int lane = t & 63;
    const int lr   = lane & 15;                    // row (A) / col (B,D)
    const int kg   = lane >> 4;

    const int rowg = r0 + lr;
    const float rc = rec[n * TOQ + rowg];
    const unsigned short* Erow = Eb + ((size_t)n * TOQ + rowg) * TIV;
    float* Prow = P + ((size_t)n * TOQ + rowg) * TIV;
    const unsigned short* VTb = VT + (size_t)n * HD * TIV;

    f32x4 acc[8];
    #pragma unroll
    for (int fn = 0; fn < 8; ++fn) acc[fn] = (f32x4)0.f;

    const int kbase = q * 256 + kg * 8;

    #pragma unroll 2
    for (int k0 = 0; k0 < 256; k0 += 32) {
        const int k = kbase + k0;
        const ushort8v ev = *(const ushort8v*)&Erow[k];
        float pv[8];
        #pragma unroll
        for (int j = 0; j < 8; ++j) pv[j] = bf2f(ev[j]) * rc;

        float4 p0, p1;
        p0.x = pv[0]; p0.y = pv[1]; p0.z = pv[2]; p0.w = pv[3];
        p1.x = pv[4]; p1.y = pv[5]; p1.z = pv[6]; p1.w = pv[7];
        *(float4*)&Prow[k]     = p0;               // P output (disjoint buffer)
        *(float4*)&Prow[k + 4] = p1;

        s16x8 a;
        #pragma unroll
        for (int j = 0; j < 8; ++j) a[j] = (short)f2bf(pv[j]);

        #pragma unroll
        for (int fn = 0; fn < 8; ++fn) {
            const s16x8 b = *(const s16x8*)&VTb[(size_t)(fn * 16 + lr) * TIV + k];
            acc[fn] = __builtin_amdgcn_mfma_f32_16x16x32_bf16(a, b, acc[fn], 0, 0, 0);
        }
    }

    // --- tree reduction 8 -> 4 -> 2 -> 1 ------------------------------------
    #define PARK(slot)                                                         \
        _Pragma("unroll") for (int fn = 0; fn < 8; ++fn)                       \
        _Pragma("unroll") for (int ri = 0; ri < 4; ++ri)                       \
            red[slot][kg * 4 + ri][fn * 16 + lr] = acc[fn][ri];
    #define GATHER(slot)                                                       \
        _Pragma("unroll") for (int fn = 0; fn < 8; ++fn)                       \
        _Pragma("unroll") for (int ri = 0; ri < 4; ++ri)                       \
            acc[fn][ri] += red[slot][kg * 4 + ri][fn * 16 + lr];

    if (q & 1) { PARK(q >> 1) }                    // 1,3,5,7 -> slots 0..3
    __syncthreads();
    if (!(q & 1)) { GATHER(q >> 1) }               // 0,2,4,6 add
    __syncthreads();
    if (!(q & 1) && (q & 2)) { PARK(q >> 2) }      // 2,6 -> slots 0,1
    __syncthreads();
    if (!(q & 3)) { GATHER(q >> 2) }               // 0,4 add
    __syncthreads();
    if (q == 4) { PARK(0) }                        // 4 -> slot 0
    __syncthreads();
    if (q == 0) {
        GATHER(0)
        #pragma unroll
        for (int fn = 0; fn < 8; ++fn) {
            #pragma unroll
            for (int ri = 0; ri < 4; ++ri) {
                const int orow = r0 + kg * 4 + ri;
                O[((size_t)n * TOQ + orow) * HD + fn * 16 + lr] = acc[fn][ri];
            }
        }
    }
    #undef PARK
    #undef GATHER
}

// ---------------------------------------------------------------------------
// K3 fallback (r11 verbatim): in-place f32 E->P, 32-row tiles.
// ---------------------------------------------------------------------------
__global__ __launch_bounds__(512) void k3_pv_old(
    float* __restrict__ EP, const unsigned short* __restrict__ VT,
    const float* __restrict__ rec, float* __restrict__ O)
{
    __shared__ float red[2][3][16][132];

    const int n    = blockIdx.y;
    const int r0   = blockIdx.x * 32;
    const int t    = threadIdx.x;
    const int wave = t >> 6;
    const int lane = t & 63;
    const int p    = wave >> 2;
    const int q    = wave & 3;
    const int lr   = lane & 15;
    const int kg   = lane >> 4;

    const int rowg = r0 + p * 16 + lr;
    const float rc = rec[n * TOQ + rowg];
    float* Erow = EP + ((size_t)n * TOQ + rowg) * TIV;
    const unsigned short* VTb = VT + (size_t)n * HD * TIV;

    f32x4 acc[8];
    #pragma unroll
    for (int fn = 0; fn < 8; ++fn) acc[fn] = (f32x4)0.f;

    const int kbase = q * 512 + kg * 8;

    #pragma unroll 2
    for (int k0 = 0; k0 < 512; k0 += 32) {
        const int k = kbase + k0;
        const float4 e0 = *(const float4*)&Erow[k];
        const float4 e1 = *(const float4*)&Erow[k + 4];
        float4 p0, p1;
        p0.x = e0.x * rc; p0.y = e0.y * rc; p0.z = e0.z * rc; p0.w = e0.w * rc;
        p1.x = e1.x * rc; p1.y = e1.y * rc; p1.z = e1.z * rc; p1.w = e1.w * rc;
        *(float4*)&Erow[k]     = p0;
        *(float4*)&Erow[k + 4] = p1;

        s16x8 a;
        a[0] = (short)f2bf(p0.x); a[1] = (short)f2bf(p0.y);
        a[2] = (short)f2bf(p0.z); a[3] = (short)f2bf(p0.w);
        a[4] = (short)f2bf(p1.x); a[5] = (short)f2bf(p1.y);
        a[6] = (short)f2bf(p1.z); a[7] = (short)f2bf(p1.w);

        #pragma unroll
        for (int fn = 0; fn < 8; ++fn) {
            const s16x8 b = *(const s16x8*)&VTb[(size_t)(fn * 16 + lr) * TIV + k];
            acc[fn] = __builtin_amdgcn_mfma_f32_16x16x32_bf16(a, b, acc[fn], 0, 0, 0);
        }
    }

    if (q != 0) {
        #pragma unroll
        for (int fn = 0; fn < 8; ++fn)
            #pragma unroll
            for (int ri = 0; ri < 4; ++ri)
                red[p][q - 1][kg * 4 + ri][fn * 16 + lr] = acc[fn][ri];
    }
    __syncthreads();
    if (q == 0) {
        #pragma unroll
        for (int fn = 0; fn < 8; ++fn) {
            #pragma unroll
            for (int ri = 0; ri < 4; ++ri) {
                const int orow = r0 + p * 16 + kg * 4 + ri;
                float o = acc[fn][ri];
                o += red[p][0][kg * 4 + ri][fn * 16 + lr];
                o += red[p][1][kg * 4 + ri][fn * 16 + lr];
                o += red[p][2][kg * 4 + ri][fn * 16 + lr];
                O[((size_t)n * TOQ + orow) * HD + fn * 16 + lr] = o;
            }
        }
    }
}

// ---------------------------------------------------------------------------
extern "C" void kernel_launch(void* const* d_in, const int* in_sizes, int n_in,
                              void* d_out, int out_size, void* d_ws, size_t ws_size,
                              hipStream_t stream)
{
    const float* Q = (const float*)d_in[0];
    const float* V = (const float*)d_in[1];
    const int*   M = (const int*)d_in[2];

    float* O = (float*)d_out;                         // [8][2048][128] f32
    float* P = O + (size_t)NB * TOQ * HD;             // [8][2048][2048] f32

    char* ws = (char*)d_ws;
    const size_t partB  = (size_t)NB * TOQ * 32 * 4;      // 2 MB
    const size_t vtB    = (size_t)NB * HD * TIV * 2;      // 4 MB
    const size_t elems  = (size_t)NB * TOQ * HD;
    const size_t sbytes = elems * 2;                      // 4 MB per split array
    const size_t ebB    = (size_t)NB * TOQ * TIV * 2;     // 67 MB bf16 E

    float*          recb = (float*)ws;
    float*          part = (float*)(ws + (1 << 16));
    unsigned short* VT   = (unsigned short*)(ws + (1 << 16) + partB);
    const size_t splitOff = (1 << 16) + partB + vtB;
    const size_t ebOff    = splitOff + 4 * sbytes;
    const size_t need2    = ebOff + ebB;                  // ~89.2 MB (proven r12+)

    k0_vt<<<dim3(TIV / 64, HD / 64, NB), 256, 0, stream>>>(V, VT);

    if (ws_size >= need2) {
        unsigned short* Qh = (unsigned short*)(ws + splitOff);
        unsigned short* Ql = (unsigned short*)(ws + splitOff + sbytes);
        unsigned short* Vh = (unsigned short*)(ws + splitOff + 2 * sbytes);
        unsigned short* Vl = (unsigned short*)(ws + splitOff + 3 * sbytes);
        unsigned short* Eb = (unsigned short*)(ws + ebOff);
        k0_split<<<dim3((unsigned)(elems / 8 / 256), 2), 256, 0, stream>>>(Q, V, Qh, Ql, Vh, Vl);
        k1_w8   <<<dim3((TIV / 128) * (TOQ / 128) * NB), 512, 0, stream>>>(Qh, Ql, Vh, Vl, M, Eb, part);
        k2_rowsum<<<dim3(NB * TOQ / 256), 256, 0, stream>>>(part, recb);
        k3_occ  <<<dim3((TOQ / 16) * NB), 512, 0, stream>>>(Eb, VT, recb, P, O);
    } else {
        k1_reg  <<<dim3(TIV / 128, TOQ / 128, NB), 256, 0, stream>>>(Q, V, M, P, part);
        k2_rowsum<<<dim3(NB * TOQ / 256), 256, 0, stream>>>(part, recb);
        k3_pv_old<<<dim3(TOQ / 32, NB), 512, 0, stream>>>(P, VT, recb, O);
    }
}